// Round 8
// baseline (56.933 us; speedup 1.0000x reference)
//
#include <hip/hip_runtime.h>
#include <hip/hip_bf16.h>

#define B_ 8
#define C_ 96
#define H_ 64
#define W_ 96
#define DD 21
#define RAWS 49            // prep LDS row stride (uints): conflict-free gather
#define RS 780             // Dst plane stride (floats): 16B-aligned, conflict-light

typedef __attribute__((ext_vector_type(8))) short sh8;
typedef __attribute__((ext_vector_type(4))) float fx4;

// Fragment-major bf16 tensors: innermost [lane(64)][e(8)] = 1KB per k-block,
// so a wave's MFMA operand load is base + lane*16B (fully coalesced).
// d1F: [b][y][p][ut(3)][k(3)][lane][8]
// d2F: [b][yp(104)][p][wt(5)][k(3)][lane][8]   (yp/x padded, borders zero)
__device__ __attribute__((aligned(16))) unsigned short g_d1F[B_*H_*2*3*3*512];
__device__ __attribute__((aligned(16))) unsigned short g_d2F[(size_t)B_*104*2*5*3*512];

// One fused prep kernel: grid (168, B).
//  t in [0,64):    d1 row y=t          -> g_d1F
//  t in [64,168):  d2 padded row yp=t-64 (zero-fill if border) -> g_d2F
__global__ __launch_bounds__(256) void prep_all(const float* __restrict__ d1,
                                                const float* __restrict__ d2) {
  __shared__ unsigned int raw[C_*RAWS];    // [c][w] packed (p0 | p1<<16)
  const int b = blockIdx.y;
  const int t = blockIdx.x;

  if (t >= 64) {
    const int yp = t - 64;
    unsigned short* ob = g_d2F + (size_t)(b*104 + yp)*(2*15*512);
    if (yp < 20 || yp >= 84) {             // border row: pure zero-fill
      uint4 z; z.x = z.y = z.z = z.w = 0u;
      for (int s = threadIdx.x; s < 1920; s += 256)
        *((uint4*)ob + s) = z;
      return;
    }
    const int y = yp - 20;
    for (int idx = threadIdx.x; idx < C_*48; idx += 256) {
      int c = idx / 48, w = idx % 48;
      const float2 v = *(const float2*)(d2 + (((b*C_ + c)*H_ + y)*W_ + 2*w));
      __hip_bfloat16 h0 = __float2bfloat16(v.x), h1 = __float2bfloat16(v.y);
      raw[c*RAWS + w] = (unsigned)*(unsigned short*)&h0 |
                        ((unsigned)*(unsigned short*)&h1 << 16);
    }
    __syncthreads();
    for (int s = threadIdx.x; s < 2*15*64; s += 256) {
      int lane = s & 63, q = s >> 6;
      int kk = q % 3, wt = (q/3) % 5, p = q / 15;
      int w = wt*16 + (lane & 15) - 10;    // x-pad: stored col = w' - 10
      int cb = kk*32 + (lane >> 4)*8;
      uint4 o; o.x = o.y = o.z = o.w = 0u;
      if (w >= 0 && w < 48) {
        unsigned short tmp[8];
        #pragma unroll
        for (int e = 0; e < 8; ++e) {
          unsigned pk = raw[(cb + e)*RAWS + w];
          tmp[e] = (unsigned short)(p ? (pk >> 16) : pk);
        }
        o = *(const uint4*)tmp;
      }
      *(uint4*)(ob + (size_t)s*8) = o;
    }
  } else {
    const int y = t;
    for (int idx = threadIdx.x; idx < C_*48; idx += 256) {
      int c = idx / 48, w = idx % 48;
      const float2 v = *(const float2*)(d1 + (((b*C_ + c)*H_ + y)*W_ + 2*w));
      __hip_bfloat16 h0 = __float2bfloat16(v.x), h1 = __float2bfloat16(v.y);
      raw[c*RAWS + w] = (unsigned)*(unsigned short*)&h0 |
                        ((unsigned)*(unsigned short*)&h1 << 16);
    }
    __syncthreads();
    unsigned short* ob = g_d1F + (size_t)(b*H_ + y)*(2*9*512);
    for (int s = threadIdx.x; s < 2*9*64; s += 256) {
      int lane = s & 63, q = s >> 6;
      int kk = q % 3, ut = (q/3) % 3, p = q / 9;
      int w = ut*16 + (lane & 15);
      int cb = kk*32 + (lane >> 4)*8;
      unsigned short tmp[8];
      #pragma unroll
      for (int e = 0; e < 8; ++e) {
        unsigned pk = raw[(cb + e)*RAWS + w];
        tmp[e] = (unsigned short)(p ? (pk >> 16) : pk);
      }
      *(uint4*)(ob + (size_t)s*8) = *(const uint4*)tmp;
    }
  }
}

// One block per (b, y8-group, i): 512 threads = 8 waves = (p, ys in [0,4)).
// Wave (p,ys) handles y = y0+2ys+{0,1}: per y, load FULL B row (15 frags,
// wt 0..4 -- kills the wt-overlap re-read), then 3 m-tiles x 9 MFMA,
// extracting into a block-wide LDS tile Dst[21][8y*96x]. One barrier, then
// each of the 21 planes is stored as a 3KB CONTIGUOUS run (vs 128B before).
// G=A.B^T band: out[b, i*21+j, y, 2u+p] = G[u, u+j], j in [0,21).
__global__ __launch_bounds__(512, 4) void corr_main(const float* __restrict__ s1,
                                                    const float* __restrict__ s2,
                                                    const float* __restrict__ os,
                                                    float* __restrict__ out) {
  __shared__ float Dst[DD*RS];             // 65520 B
  const int gid = blockIdx.x;
  const int b = gid & 7;                   // XCD affinity
  const int yg = (gid >> 3) & 7;
  const int i  = gid >> 6;                 // [0,21)
  const int y0 = yg*8;
  const int wv = threadIdx.x >> 6;
  const int p = wv & 1, ys = wv >> 1;
  const int lane = threadIdx.x & 63;
  const int lr = lane & 15, lg = lane >> 4;
  const int jbase = lr - 4*lg;
  const float scale = s1[0]*s2[0] / (96.0f * os[0]);

  #pragma unroll
  for (int yi = 0; yi < 2; ++yi) {
    const int yl = 2*ys + yi;
    const int y = y0 + yl;

    // full B row for yp = y + 2i: 15 fragments (wt 0..4, k 0..2)
    sh8 Bf[15];
    {
      const unsigned short* rb =
          g_d2F + (size_t)((b*104 + y + 2*i)*2 + p)*(15*512) + lane*8;
      #pragma unroll
      for (int t = 0; t < 15; ++t)
        Bf[t] = *(const sh8*)(rb + t*512);
    }

    const unsigned short* aRow =
        g_d1F + (size_t)((b*H_ + y)*2 + p)*(9*512) + lane*8;

    #pragma unroll
    for (int mt = 0; mt < 3; ++mt) {
      sh8 aF[3];
      #pragma unroll
      for (int k = 0; k < 3; ++k)
        aF[k] = *(const sh8*)(aRow + (mt*3 + k)*512);

      fx4 acc[3] = {fx4{0,0,0,0}, fx4{0,0,0,0}, fx4{0,0,0,0}};
      #pragma unroll
      for (int k = 0; k < 3; ++k)
        #pragma unroll
        for (int n = 0; n < 3; ++n)
          acc[n] = __builtin_amdgcn_mfma_f32_16x16x32_bf16(aF[k], Bf[(mt+n)*3+k],
                                                           acc[n], 0, 0, 0);

      // band extract: col w' = 16(mt+n)+lr, row u = 16mt+4lg+r ; j = w'-u
      // x = 2u+p ; c = yl*96+x ; XOR swizzle (j&7)<<2 breaks bank lattice
      const int cb = yl*96 + 32*mt + 8*lg + p;
      #pragma unroll
      for (int n = 0; n < 3; ++n)
        #pragma unroll
        for (int r = 0; r < 4; ++r) {
          int j = jbase + 16*n - r;
          if (j >= 0 && j < DD) {
            int c = cb + 2*r;
            Dst[j*RS + (c ^ ((j & 7) << 2))] = acc[n][r];
          }
        }
    }
  }
  __syncthreads();

  // store: 21 planes x 768 floats; each plane is 3072B CONTIGUOUS in HBM
  const size_t obase = ((size_t)(b*441 + i*DD)*H_ + y0)*W_;
  for (int s = threadIdx.x; s < DD*192; s += 512) {
    int j = s / 192, q = (s % 192)*4;
    fx4 v = *(const fx4*)&Dst[j*RS + (q ^ ((j & 7) << 2))];
    v = v * scale;
    *(fx4*)(out + obase + (size_t)j*(H_*W_) + q) = v;
  }
}

extern "C" void kernel_launch(void* const* d_in, const int* in_sizes, int n_in,
                              void* d_out, int out_size, void* d_ws, size_t ws_size,
                              hipStream_t stream) {
  const float* d1 = (const float*)d_in[0];
  const float* d2 = (const float*)d_in[1];
  const float* s1 = (const float*)d_in[2];
  const float* s2 = (const float*)d_in[3];
  const float* os = (const float*)d_in[5];   // inter_scale (d_in[4]) unused

  prep_all<<<dim3(168, B_), 256, 0, stream>>>(d1, d2);
  corr_main<<<B_*8*DD, 512, 0, stream>>>(s1, s2, os, (float*)d_out);
}

// Round 9
// 51.990 us; speedup vs baseline: 1.0951x; 1.0951x over previous
//
#include <hip/hip_runtime.h>
#include <hip/hip_bf16.h>

#define B_ 8
#define C_ 96
#define H_ 64
#define W_ 96
#define DD 21
#define NI 3               // i-values per block
#define ISPLIT 7           // 21 / NI
#define LDSTw 37           // per-wave Dst row stride (floats): 5 mod 32, conflict-light
#define RAWS 49            // prep LDS row stride (uints): conflict-free gather

typedef __attribute__((ext_vector_type(8))) short sh8;
typedef __attribute__((ext_vector_type(4))) float fx4;

// Fragment-major bf16 tensors: innermost [lane(64)][e(8)] = 1KB per k-block,
// so a wave's MFMA operand load is base + lane*16B (fully coalesced).
// d1F: [b][y][p][ut(3)][k(3)][lane][8]
// d2F: [b][yp(104)][p][wt(5)][k(3)][lane][8]   (yp/x padded, borders zero)
__device__ __attribute__((aligned(16))) unsigned short g_d1F[B_*H_*2*3*3*512];
__device__ __attribute__((aligned(16))) unsigned short g_d2F[(size_t)B_*104*2*5*3*512];

// Fused prep kernel, XCD-aligned: gid = b + 8*t so batch b's rows are written
// from XCD b (matches corr_main's b = gid&7 -> producer/consumer same L2).
//  t in [0,64):    d1 row y=t          -> g_d1F
//  t in [64,168):  d2 padded row yp=t-64 (zero-fill if border) -> g_d2F
__global__ __launch_bounds__(256) void prep_all(const float* __restrict__ d1,
                                                const float* __restrict__ d2) {
  __shared__ unsigned int raw[C_*RAWS];    // [c][w] packed (p0 | p1<<16)
  const int b = blockIdx.x & 7;
  const int t = blockIdx.x >> 3;

  if (t >= 64) {
    const int yp = t - 64;
    unsigned short* ob = g_d2F + (size_t)(b*104 + yp)*(2*15*512);
    if (yp < 20 || yp >= 84) {             // border row: pure zero-fill
      uint4 z; z.x = z.y = z.z = z.w = 0u;
      for (int s = threadIdx.x; s < 1920; s += 256)
        *((uint4*)ob + s) = z;
      return;
    }
    const int y = yp - 20;
    for (int idx = threadIdx.x; idx < C_*48; idx += 256) {
      int c = idx / 48, w = idx % 48;
      const float2 v = *(const float2*)(d2 + (((b*C_ + c)*H_ + y)*W_ + 2*w));
      __hip_bfloat16 h0 = __float2bfloat16(v.x), h1 = __float2bfloat16(v.y);
      raw[c*RAWS + w] = (unsigned)*(unsigned short*)&h0 |
                        ((unsigned)*(unsigned short*)&h1 << 16);
    }
    __syncthreads();
    for (int s = threadIdx.x; s < 2*15*64; s += 256) {
      int lane = s & 63, q = s >> 6;
      int kk = q % 3, wt = (q/3) % 5, p = q / 15;
      int w = wt*16 + (lane & 15) - 10;    // x-pad: stored col = w' - 10
      int cb = kk*32 + (lane >> 4)*8;
      uint4 o; o.x = o.y = o.z = o.w = 0u;
      if (w >= 0 && w < 48) {
        unsigned short tmp[8];
        #pragma unroll
        for (int e = 0; e < 8; ++e) {
          unsigned pk = raw[(cb + e)*RAWS + w];
          tmp[e] = (unsigned short)(p ? (pk >> 16) : pk);
        }
        o = *(const uint4*)tmp;
      }
      *(uint4*)(ob + (size_t)s*8) = o;
    }
  } else {
    const int y = t;
    for (int idx = threadIdx.x; idx < C_*48; idx += 256) {
      int c = idx / 48, w = idx % 48;
      const float2 v = *(const float2*)(d1 + (((b*C_ + c)*H_ + y)*W_ + 2*w));
      __hip_bfloat16 h0 = __float2bfloat16(v.x), h1 = __float2bfloat16(v.y);
      raw[c*RAWS + w] = (unsigned)*(unsigned short*)&h0 |
                        ((unsigned)*(unsigned short*)&h1 << 16);
    }
    __syncthreads();
    unsigned short* ob = g_d1F + (size_t)(b*H_ + y)*(2*9*512);
    for (int s = threadIdx.x; s < 2*9*64; s += 256) {
      int lane = s & 63, q = s >> 6;
      int kk = q % 3, ut = (q/3) % 3, p = q / 9;
      int w = ut*16 + (lane & 15);
      int cb = kk*32 + (lane >> 4)*8;
      unsigned short tmp[8];
      #pragma unroll
      for (int e = 0; e < 8; ++e) {
        unsigned pk = raw[(cb + e)*RAWS + w];
        tmp[e] = (unsigned short)(p ? (pk >> 16) : pk);
      }
      *(uint4*)(ob + (size_t)s*8) = *(const uint4*)tmp;
    }
  }
}

// BARRIER-FREE corr: one wave owns BOTH parities of one (mt, y, i-range), so
// it produces the full contiguous 32-float x-range of each of its 21 output
// rows. The extract->coalesce transpose goes through a WAVE-PRIVATE LDS
// region: within-wave ds_write->ds_read ordering needs only lgkmcnt (compiler
// auto-inserts), no s_barrier anywhere. 256-thr block = 4 independent waves
// (4 consecutive y). Iterations pipeline freely (no sync points).
// G=A.B^T band: out[b, i*21+j, y, 2u+p] = G_p[u, u+j], j in [0,21).
__global__ __launch_bounds__(256, 3) void corr_main(const float* __restrict__ s1,
                                                    const float* __restrict__ s2,
                                                    const float* __restrict__ os,
                                                    float* __restrict__ out) {
  __shared__ float Dst[4][DD*LDSTw];       // per-wave private regions (12.4 KB)
  const int gid = blockIdx.x;
  const int b = gid & 7;                   // XCD affinity
  int t = gid >> 3;
  const int mt = t % 3; t /= 3;
  const int m0 = mt << 4;
  const int yg = t & 15;                   // 16 groups of 4 y
  const int i0 = (t >> 4) * NI;
  const int wv = threadIdx.x >> 6;
  const int y = yg*4 + wv;
  const int lane = threadIdx.x & 63;
  const int lr = lane & 15, lg = lane >> 4;
  const int jbase = lr - 4*lg;
  const float scale = s1[0]*s2[0] / (96.0f * os[0]);
  float* dst = Dst[wv];

  // A fragments, both parities (constant across i)
  sh8 aF0[3], aF1[3];
  {
    const unsigned short* a0 =
        g_d1F + (size_t)((b*H_ + y)*2)*(9*512) + mt*3*512 + lane*8;
    #pragma unroll
    for (int k = 0; k < 3; ++k) {
      aF0[k] = *(const sh8*)(a0 + k*512);
      aF1[k] = *(const sh8*)(a0 + 9*512 + k*512);
    }
  }

  #pragma unroll
  for (int it = 0; it < NI; ++it) {
    const int i = i0 + it;
    const int row = y + 2*i;
    const unsigned short* rb0 =
        g_d2F + (size_t)((b*104 + row)*2*5 + mt)*(3*512) + lane*8;
    sh8 bF0[9], bF1[9];
    #pragma unroll
    for (int n = 0; n < 3; ++n)
      #pragma unroll
      for (int k = 0; k < 3; ++k) {
        bF0[k*3+n] = *(const sh8*)(rb0 + (n*3 + k)*512);
        bF1[k*3+n] = *(const sh8*)(rb0 + 15*512 + (n*3 + k)*512);
      }

    fx4 acc0[3] = {fx4{0,0,0,0}, fx4{0,0,0,0}, fx4{0,0,0,0}};
    fx4 acc1[3] = {fx4{0,0,0,0}, fx4{0,0,0,0}, fx4{0,0,0,0}};
    #pragma unroll
    for (int k = 0; k < 3; ++k)
      #pragma unroll
      for (int n = 0; n < 3; ++n) {
        acc0[n] = __builtin_amdgcn_mfma_f32_16x16x32_bf16(aF0[k], bF0[k*3+n],
                                                          acc0[n], 0, 0, 0);
        acc1[n] = __builtin_amdgcn_mfma_f32_16x16x32_bf16(aF1[k], bF1[k*3+n],
                                                          acc1[n], 0, 0, 0);
      }

    // band extract into wave-private Dst: col w'=m0+16n+lr, row u=m0+4lg+r,
    // j=w'-u ; xl = 8lg+2r+p in [0,32)
    #pragma unroll
    for (int n = 0; n < 3; ++n)
      #pragma unroll
      for (int r = 0; r < 4; ++r) {
        int j = jbase + 16*n - r;
        if (j >= 0 && j < DD) {
          dst[j*LDSTw + 8*lg + 2*r]     = acc0[n][r];
          dst[j*LDSTw + 8*lg + 2*r + 1] = acc1[n][r];
        }
      }

    // coalesced store, same wave (lgkmcnt-ordered, NO barrier):
    // 21 planes x 32 floats = 168 fx4; 8 lanes per plane -> 128B runs
    const size_t obase = ((size_t)(b*441 + i*DD)*H_ + y)*W_ + 2*m0;
    #pragma unroll
    for (int s = 0; s < 3; ++s) {
      int q = lane + s*64;
      if (q < DD*8) {
        int j = q >> 3, xi = q & 7;
        fx4 v = *(const fx4*)&dst[j*LDSTw + xi*4];
        v = v * scale;
        *(fx4*)(out + obase + (size_t)j*(H_*W_) + xi*4) = v;
      }
    }
  }
}

extern "C" void kernel_launch(void* const* d_in, const int* in_sizes, int n_in,
                              void* d_out, int out_size, void* d_ws, size_t ws_size,
                              hipStream_t stream) {
  const float* d1 = (const float*)d_in[0];
  const float* d2 = (const float*)d_in[1];
  const float* s1 = (const float*)d_in[2];
  const float* s2 = (const float*)d_in[3];
  const float* os = (const float*)d_in[5];   // inter_scale (d_in[4]) unused

  prep_all<<<168*B_, 256, 0, stream>>>(d1, d2);
  corr_main<<<B_*3*16*ISPLIT, 256, 0, stream>>>(s1, s2, os, (float*)d_out);
}

// Round 10
// 48.853 us; speedup vs baseline: 1.1654x; 1.0642x over previous
//
#include <hip/hip_runtime.h>
#include <hip/hip_bf16.h>

#define B_ 8
#define C_ 96
#define H_ 64
#define W_ 96
#define DD 21
#define NI 3               // i-values per block
#define ISPLIT 7           // 21 / NI
#define LDSTm 37           // Dst row stride (floats): 5 mod 32 -> conflict-light scatter
#define RAWS 49            // prep LDS row stride (uints): conflict-free gather

typedef __attribute__((ext_vector_type(8))) short sh8;
typedef __attribute__((ext_vector_type(4))) float fx4;

// Fragment-major bf16 tensors: innermost [lane(64)][e(8)] = 1KB per k-block,
// so a wave's MFMA operand load is base + lane*16B (fully coalesced).
// d1F: [b][y][p][ut(3)][k(3)][lane][8]
// d2F: [b][yp(104)][p][wt(5)][k(3)][lane][8]   (yp/x padded, borders zero)
__device__ __attribute__((aligned(16))) unsigned short g_d1F[B_*H_*2*3*3*512];
__device__ __attribute__((aligned(16))) unsigned short g_d2F[(size_t)B_*104*2*5*3*512];

// One fused prep kernel: grid (168, B).
//  t in [0,64):    d1 row y=t          -> g_d1F
//  t in [64,168):  d2 padded row yp=t-64 (zero-fill if border) -> g_d2F
__global__ __launch_bounds__(256) void prep_all(const float* __restrict__ d1,
                                                const float* __restrict__ d2) {
  __shared__ unsigned int raw[C_*RAWS];    // [c][w] packed (p0 | p1<<16)
  const int b = blockIdx.y;
  const int t = blockIdx.x;

  if (t >= 64) {
    const int yp = t - 64;
    unsigned short* ob = g_d2F + (size_t)(b*104 + yp)*(2*15*512);
    if (yp < 20 || yp >= 84) {             // border row: pure zero-fill
      uint4 z; z.x = z.y = z.z = z.w = 0u;
      for (int s = threadIdx.x; s < 1920; s += 256)
        *((uint4*)ob + s) = z;
      return;
    }
    const int y = yp - 20;
    for (int idx = threadIdx.x; idx < C_*48; idx += 256) {
      int c = idx / 48, w = idx % 48;
      const float2 v = *(const float2*)(d2 + (((b*C_ + c)*H_ + y)*W_ + 2*w));
      __hip_bfloat16 h0 = __float2bfloat16(v.x), h1 = __float2bfloat16(v.y);
      raw[c*RAWS + w] = (unsigned)*(unsigned short*)&h0 |
                        ((unsigned)*(unsigned short*)&h1 << 16);
    }
    __syncthreads();
    for (int s = threadIdx.x; s < 2*15*64; s += 256) {
      int lane = s & 63, q = s >> 6;
      int kk = q % 3, wt = (q/3) % 5, p = q / 15;
      int w = wt*16 + (lane & 15) - 10;    // x-pad: stored col = w' - 10
      int cb = kk*32 + (lane >> 4)*8;
      uint4 o; o.x = o.y = o.z = o.w = 0u;
      if (w >= 0 && w < 48) {
        unsigned short tmp[8];
        #pragma unroll
        for (int e = 0; e < 8; ++e) {
          unsigned pk = raw[(cb + e)*RAWS + w];
          tmp[e] = (unsigned short)(p ? (pk >> 16) : pk);
        }
        o = *(const uint4*)tmp;
      }
      *(uint4*)(ob + (size_t)s*8) = o;
    }
  } else {
    const int y = t;
    for (int idx = threadIdx.x; idx < C_*48; idx += 256) {
      int c = idx / 48, w = idx % 48;
      const float2 v = *(const float2*)(d1 + (((b*C_ + c)*H_ + y)*W_ + 2*w));
      __hip_bfloat16 h0 = __float2bfloat16(v.x), h1 = __float2bfloat16(v.y);
      raw[c*RAWS + w] = (unsigned)*(unsigned short*)&h0 |
                        ((unsigned)*(unsigned short*)&h1 << 16);
    }
    __syncthreads();
    unsigned short* ob = g_d1F + (size_t)(b*H_ + y)*(2*9*512);
    for (int s = threadIdx.x; s < 2*9*64; s += 256) {
      int lane = s & 63, q = s >> 6;
      int kk = q % 3, ut = (q/3) % 3, p = q / 9;
      int w = ut*16 + (lane & 15);
      int cb = kk*32 + (lane >> 4)*8;
      unsigned short tmp[8];
      #pragma unroll
      for (int e = 0; e < 8; ++e) {
        unsigned pk = raw[(cb + e)*RAWS + w];
        tmp[e] = (unsigned short)(p ? (pk >> 16) : pk);
      }
      *(uint4*)(ob + (size_t)s*8) = *(const uint4*)tmp;
    }
  }
}

// LDS-only barrier: orders extract(ds_write) -> store(ds_read) across the
// block WITHOUT draining vmcnt -- prefetched global loads stay in flight
// across the barrier (the compiler auto-waits the right vmcnt before the
// MFMAs that consume them). "memory" clobber pins LDS ops on both sides.
#define SYNC_LDS asm volatile("s_waitcnt lgkmcnt(0)\n\ts_barrier" ::: "memory")

// Token-pasting macros over NAMED register arrays (bF0/bF1): every array
// index is compile-time after unroll -> no scratch (rule #20; R5 lesson).
#define LOADB(BF, ROW) do {                                                    \
    const unsigned short* rb_ =                                                \
        g_d2F + (size_t)(((b*104 + (ROW))*2 + p)*5 + mt)*(3*512) + lane*8;     \
    _Pragma("unroll")                                                          \
    for (int n_ = 0; n_ < 3; ++n_)                                             \
      _Pragma("unroll")                                                        \
      for (int k_ = 0; k_ < 3; ++k_)                                           \
        BF[k_*3+n_] = *(const sh8*)(rb_ + (n_*3 + k_)*512);                    \
  } while (0)

// Output stores are NON-TEMPORAL (nt flag): d_out is write-once/never-read,
// so bypassing L2 allocation keeps d2F resident per-XCD -> B-fragment reads
// stay L2-hits instead of eviction-missing to L3/HBM. (This round's A/B.)
#define COMBO(BF, I, BUF) do {                                                 \
    fx4 acc[3] = {fx4{0,0,0,0}, fx4{0,0,0,0}, fx4{0,0,0,0}};                   \
    _Pragma("unroll")                                                          \
    for (int k_ = 0; k_ < 3; ++k_)                                             \
      _Pragma("unroll")                                                        \
      for (int n_ = 0; n_ < 3; ++n_)                                           \
        acc[n_] = __builtin_amdgcn_mfma_f32_16x16x32_bf16(aF[k_], BF[k_*3+n_], \
                                                          acc[n_], 0, 0, 0);   \
    _Pragma("unroll")                                                          \
    for (int n_ = 0; n_ < 3; ++n_)                                             \
      _Pragma("unroll")                                                        \
      for (int r_ = 0; r_ < 4; ++r_) {                                         \
        int j_ = 16*n_ + lr - 4*lg - r_;                                       \
        if (j_ >= 0 && j_ < DD)                                                \
          Dst[BUF][j_*LDSTm + 2*(4*lg + r_) + p] = acc[n_][r_];                \
      }                                                                        \
    SYNC_LDS;                                                                  \
    size_t obase = (size_t)((b*441 + (I)*DD)*H_ + y)*W_ + 2*m0;                \
    for (int s_ = threadIdx.x; s_ < DD*32; s_ += 128) {                        \
      int j_ = s_ >> 5, xl_ = s_ & 31;                                         \
      __builtin_nontemporal_store(Dst[BUF][j_*LDSTm + xl_]*scale,              \
                                  out + obase + (size_t)j_*(H_*W_) + xl_);     \
    }                                                                          \
  } while (0)
// Dst ping-pong race check: extract into BUF happens only after the barrier
// that followed the previous store of the SAME buffer (two combos earlier)
// -- race-free with one LDS barrier per combo.

// One block per (b, m-tile, y, i-segment): 128 threads = 2 waves (p=0,1).
// Wave (p): A[u][c]=d1[b,c,y,2u+p], u in [m0,m0+16); B[w'][c]=d2pad[...,2w'+p].
// G=A·B^T band: out[b, i*21+j, y, 2u+p] = G[u, u+j], j in [0,21).
// B rows register-double-buffered: LOADB(next) issues before COMBO(cur), and
// SYNC_LDS lets those loads stay outstanding across the barrier.
__global__ __launch_bounds__(128, 4) void corr_main(const float* __restrict__ s1,
                                                    const float* __restrict__ s2,
                                                    const float* __restrict__ os,
                                                    float* __restrict__ out) {
  __shared__ float Dst[2][DD*LDSTm];
  const int gid = blockIdx.x;
  const int b = gid & 7;                   // XCD affinity
  int t = gid >> 3;
  const int mt = t % 3; t /= 3;
  const int m0 = mt << 4;
  const int y = t & 63;
  const int i0 = (t >> 6) * NI;
  const int p = threadIdx.x >> 6;
  const int lane = threadIdx.x & 63;
  const int lr = lane & 15, lg = lane >> 4;
  const float scale = s1[0]*s2[0] / (96.0f * os[0]);

  sh8 aF[3];
  {
    const unsigned short* aB =
        g_d1F + (size_t)((b*H_ + y)*2 + p)*(9*512) + (size_t)mt*3*512 + lane*8;
    #pragma unroll
    for (int k = 0; k < 3; ++k)
      aF[k] = *(const sh8*)(aB + k*512);
  }

  sh8 bF0[9], bF1[9];
  const int yb = y + 2*i0;                 // B row for i0 (rows step by 2)
  LOADB(bF0, yb);
  LOADB(bF1, yb + 2);
  COMBO(bF0, i0,     0);
  LOADB(bF0, yb + 4);
  COMBO(bF1, i0 + 1, 1);
  COMBO(bF0, i0 + 2, 0);
}

extern "C" void kernel_launch(void* const* d_in, const int* in_sizes, int n_in,
                              void* d_out, int out_size, void* d_ws, size_t ws_size,
                              hipStream_t stream) {
  const float* d1 = (const float*)d_in[0];
  const float* d2 = (const float*)d_in[1];
  const float* s1 = (const float*)d_in[2];
  const float* s2 = (const float*)d_in[3];
  const float* os = (const float*)d_in[5];   // inter_scale (d_in[4]) unused

  prep_all<<<dim3(168, B_), 256, 0, stream>>>(d1, d2);
  corr_main<<<B_*3*H_*ISPLIT, 128, 0, stream>>>(s1, s2, os, (float*)d_out);
}